// Round 2
// baseline (408.102 us; speedup 1.0000x reference)
//
#include <hip/hip_runtime.h>
#include <hip/hip_bf16.h>

#define B_SZ 8192
#define DIMS 1024
#define CLN 8
#define BM 128
#define PADMAX (B_SZ + CLN * BM)     // 9216
#define MAX_TILES (B_SZ / BM + CLN)  // 72

typedef __attribute__((ext_vector_type(8))) __bf16 bf16x8;
typedef __attribute__((ext_vector_type(8))) short short8;
typedef __attribute__((ext_vector_type(4))) short short4v;
typedef __attribute__((ext_vector_type(4))) float f32x4;

__device__ __forceinline__ short f2bf(float f) {
  __hip_bfloat16 h = __float2bfloat16(f);
  return __builtin_bit_cast(short, h);
}
__device__ __forceinline__ float bf2f(short s) {
  unsigned u = ((unsigned)(unsigned short)s) << 16;
  return __builtin_bit_cast(float, u);
}

// async 16B/lane global->LDS DMA. LDS dest is wave-uniform base; HW adds lane*16.
__device__ __forceinline__ void gl_lds16(const short* g, short* l) {
  __builtin_amdgcn_global_load_lds(
      (const __attribute__((address_space(1))) unsigned int*)(unsigned long long)(uintptr_t)g,
      (__attribute__((address_space(3))) unsigned int*)(unsigned long long)(uintptr_t)l,
      16, 0, 0);
}

// ---- router: 4 waves/block, 1 sample/wave, fused fp32->bf16 of x ----
__global__ void router_kernel(const float* __restrict__ x, const float* __restrict__ center,
                              int* __restrict__ router, short* __restrict__ xb) {
  const int bx = blockIdx.x;
  const int tid = threadIdx.x;
  const int lane = tid & 63;
  const int w = tid >> 6;
  const int s = bx * 4 + w;
  const float4* xr = (const float4*)(x + (size_t)s * DIMS);
  float4 xv[4];
#pragma unroll
  for (int j = 0; j < 4; ++j) xv[j] = xr[j * 64 + lane];
  if (xb) {
    short* xbr = xb + (size_t)s * DIMS;
#pragma unroll
    for (int j = 0; j < 4; ++j) {
      short4v sv;
      sv[0] = f2bf(xv[j].x); sv[1] = f2bf(xv[j].y);
      sv[2] = f2bf(xv[j].z); sv[3] = f2bf(xv[j].w);
      *(short4v*)(xbr + j * 256 + lane * 4) = sv;
    }
  }
  float p[CLN];
#pragma unroll
  for (int c = 0; c < CLN; ++c) {
    const float4* cr = (const float4*)(center + (size_t)c * DIMS);
    float acc = 0.f;
#pragma unroll
    for (int j = 0; j < 4; ++j) {
      float4 cv = cr[j * 64 + lane];
      acc += xv[j].x * cv.x + xv[j].y * cv.y + xv[j].z * cv.z + xv[j].w * cv.w;
    }
    p[c] = acc;
  }
#pragma unroll
  for (int c = 0; c < CLN; ++c) {
#pragma unroll
    for (int m = 1; m < 64; m <<= 1) p[c] += __shfl_xor(p[c], m);
  }
  if (lane == 0) {
    int best = 0; float bv = p[0];
#pragma unroll
    for (int c = 1; c < CLN; ++c) { if (p[c] > bv) { bv = p[c]; best = c; } }
    router[s] = best;
  }
}

// ---- gate body: gwt[c][n][k] = bf16(w0[k][n]*wc[c][k][n]) ----
// 128k x 64n tile per block. Round-7: block order n0-FASTEST — concurrent
// blocks of one k-group read rows k0..k0+127 of w0/wc fully contiguously
// (32 x 256 B = whole 8-KB rows) -> DRAM page locality on the 151-MB wc
// stream. (k-fastest measured 2.1 TB/s = activation-bound signature.)
// Phase 1: 16 outstanding dwordx4 loads/thread, pack k-octets -> ds_write_b128
//          into XOR-swizzled [64][128] layout (cb ^= row&15).
// Phase 2: 4x ds_read_b128 -> 64 B/thread contiguous global store.
template <int K, int N>
__device__ __forceinline__ void gate_body(const float* __restrict__ w0,
                                          const float* __restrict__ wc,
                                          short* __restrict__ gwt, int bx, short* lds) {
  constexpr int KB = K / 128, NB = N / 64;
  const int c = bx / (KB * NB);
  const int rem = bx % (KB * NB);
  const int k0 = (rem / NB) * 128;   // k slowest
  const int n0 = (rem % NB) * 64;    // n fastest: co-resident blocks read
                                     // contiguous n-spans of the same k rows
  const int tid = threadIdx.x;
  // phase 1: thread (i = tid&15 -> n-quad, q = tid>>4 -> k-octet) loads 8 rows x float4
  const int i = tid & 15;
  const int q = tid >> 4;
  const float* w0p = w0 + (size_t)(k0 + q * 8) * N + n0 + i * 4;
  const float* wcp = wc + ((size_t)c * K + k0 + q * 8) * N + n0 + i * 4;
  float4 a[8], b[8];
#pragma unroll
  for (int j = 0; j < 8; ++j) {
    a[j] = *(const float4*)(w0p + (size_t)j * N);
    b[j] = *(const float4*)(wcp + (size_t)j * N);
  }
#pragma unroll
  for (int jj = 0; jj < 4; ++jj) {
    const int r = i * 4 + jj;        // n-row within tile
    short8 v;
#pragma unroll
    for (int j = 0; j < 8; ++j) {
      const float* af = (const float*)&a[j];
      const float* bf = (const float*)&b[j];
      v[j] = f2bf(af[jj] * bf[jj]);
    }
    const int sw = q ^ (r & 15);     // swizzled col-block
    *(short8*)&lds[r * 128 + sw * 8] = v;
  }
  __syncthreads();
  // phase 2: thread (n = tid>>2, seg = tid&3) reads 32 shorts, stores 64 B
  const int n = tid >> 2;
  const int seg = tid & 3;
  short8 rv[4];
#pragma unroll
  for (int u = 0; u < 4; ++u) {
    const int cb = seg * 4 + u;
    const int sw = cb ^ (n & 15);
    rv[u] = *(const short8*)&lds[n * 128 + sw * 8];
  }
  short* dst = gwt + ((size_t)c * N + n0 + n) * K + k0 + seg * 32;
#pragma unroll
  for (int u = 0; u < 4; ++u) *(short8*)(dst + u * 8) = rv[u];
}

// ---- all three gate layers in one kernel (split from router for attribution) ----
// L0: 8*32*8=2048, L1: 16*16*8=2048, L2: 8*8*8=512 gate blocks (4608 total).
__global__ void gate_kernel(const float* w00, const float* wc0, short* g0,
                            const float* w01, const float* wc1, short* g1,
                            const float* w02, const float* wc2, short* g2) {
  __shared__ short lds[64 * 128];
  const int gx = blockIdx.x;
  if (gx < 2048)       gate_body<1024, 2048>(w00, wc0, g0, gx, lds);
  else if (gx < 4096)  gate_body<2048, 1024>(w01, wc1, g1, gx - 2048, lds);
  else                 gate_body<1024, 512>(w02, wc2, g2, gx - 4096, lds);
}

// tier-1 single-layer gate
template <int K, int N>
__global__ void gate1_kernel(const float* __restrict__ w0, const float* __restrict__ wc,
                             short* __restrict__ gwt) {
  __shared__ short lds[64 * 128];
  gate_body<K, N>(w0, wc, gwt, blockIdx.x, lds);
}

// ---- mono-block counting sort + zero z ----
__global__ void sort_kernel(const int* __restrict__ router, int* __restrict__ counts,
                            int* __restrict__ pstart, int* __restrict__ meta,
                            int* __restrict__ tile_c, int* __restrict__ tile_r,
                            int* __restrict__ order, float* __restrict__ z) {
  __shared__ int bins[CLN];
  __shared__ int cur[CLN];
  __shared__ int ps_s[CLN + 1];
  const int t = threadIdx.x;
  const int lane = t & 63;
  for (int p = t; p < PADMAX; p += 1024) z[p] = 0.f;   // gemm2 dot-accumulator
  if (t < CLN) bins[t] = 0;
  __syncthreads();
  int myc[8];
#pragma unroll
  for (int j = 0; j < 8; ++j) myc[j] = router[t + 1024 * j];
#pragma unroll
  for (int j = 0; j < 8; ++j) {
#pragma unroll
    for (int c = 0; c < CLN; ++c) {
      unsigned long long m = __ballot(myc[j] == c);
      if (lane == 0 && m) atomicAdd(&bins[c], __popcll(m));
    }
  }
  __syncthreads();
  if (t == 0) {
    int ps = 0, nt = 0;
    for (int c = 0; c < CLN; ++c) {
      const int tot = bins[c];
      counts[c] = tot; pstart[c] = ps; ps_s[c] = ps; cur[c] = 0;
      const int tiles = (tot + BM - 1) / BM;
      for (int i = 0; i < tiles; ++i) { tile_c[nt] = c; tile_r[nt] = ps + i * BM; ++nt; }
      ps += tiles * BM;
    }
    pstart[CLN] = ps; ps_s[CLN] = ps; meta[0] = nt; meta[1] = ps;
  }
  __syncthreads();
#pragma unroll
  for (int j = 0; j < 8; ++j) {
    const int s = t + 1024 * j;
    const int c = myc[j];
    int pos = 0;
#pragma unroll
    for (int cc = 0; cc < CLN; ++cc) {
      unsigned long long m = __ballot(c == cc);
      int b = 0;
      if (lane == 0 && m) b = atomicAdd(&cur[cc], __popcll(m));
      b = __shfl(b, 0);
      if (c == cc) pos = ps_s[cc] + b + __popcll(m & ((1ull << lane) - 1ull));
    }
    order[pos] = s;
  }
  __syncthreads();
  for (int p = t; p < PADMAX; p += 1024) {
#pragma unroll
    for (int c = 0; c < CLN; ++c) {
      if (p >= ps_s[c] && p < ps_s[c + 1]) {
        if (p - ps_s[c] >= bins[c]) order[p] = order[ps_s[c]];
        break;
      }
    }
  }
}

// -------- GEMM: BK=32 (round-4-measured), global_load_lds(16B), bf16 --------
// 128x128 tile, 4 waves (2x2 of 64x64), mfma_f32_16x16x32_bf16.
// 1-D grid, n0 fastest: B-slice sharers (stride NT = 0 mod 8) pin to one XCD.
// FUSE_DOT (layer 2): epilogue computes gated w3 dot per row + atomicAdd to z
// instead of writing h2 (saves 19 MB write + re-read + a kernel).
template <int K, int N, bool GATHER, bool FUSE_DOT>
__global__ void gemm_async(const short* __restrict__ Abase, const short* __restrict__ gwt,
                           short* __restrict__ Aout, const int* __restrict__ order,
                           const int* __restrict__ tile_c, const int* __restrict__ tile_r,
                           const int* __restrict__ meta,
                           const float* __restrict__ w03, const float* __restrict__ wc3,
                           float* __restrict__ z) {
  constexpr int NT = N / 128;
  const int bt = blockIdx.x / NT;
  if (bt >= meta[0]) return;
  const int n0 = (blockIdx.x % NT) * 128;
  const int cl = tile_c[bt];
  const int row0 = tile_r[bt];

  __shared__ __align__(16) short As[128 * 32];
  __shared__ __align__(16) short Bs[128 * 32];  // Bs[n][k]

  const int tid = threadIdx.x;
  const int lane = tid & 63;
  const int w = tid >> 6;
  const int wm = w >> 1;
  const int wn = w & 1;

  const int lrow = lane >> 2;
  const int kofs = (lane & 3) << 3;
  const short* ga0;
  const short* ga1;
  if (GATHER) {
    ga0 = Abase + (size_t)order[row0 + w * 16 + lrow] * K + kofs;
    ga1 = Abase + (size_t)order[row0 + 64 + w * 16 + lrow] * K + kofs;
  } else {
    ga0 = Abase + (size_t)(row0 + w * 16 + lrow) * K + kofs;
    ga1 = ga0 + (size_t)64 * K;
  }
  const short* gb0 = gwt + ((size_t)cl * N + n0 + w * 16 + lrow) * K + kofs;
  const short* gb1 = gb0 + (size_t)64 * K;
  short* lA0 = &As[w * 16 * 32];
  short* lA1 = &As[(64 + w * 16) * 32];
  short* lB0 = &Bs[w * 16 * 32];
  short* lB1 = &Bs[(64 + w * 16) * 32];

  f32x4 acc[4][4] = {};
  const int arL = wm * 64 + (lane & 15);
  const int bcL = wn * 64 + (lane & 15);
  const int kq = (lane >> 4) << 3;

  for (int kb = 0; kb < K; kb += 32) {
    __syncthreads();
    gl_lds16(ga0 + kb, lA0);
    gl_lds16(ga1 + kb, lA1);
    gl_lds16(gb0 + kb, lB0);
    gl_lds16(gb1 + kb, lB1);
    __syncthreads();

    short8 af[4], bfr[4];
#pragma unroll
    for (int mi = 0; mi < 4; ++mi) af[mi] = *(const short8*)&As[(arL + mi * 16) * 32 + kq];
#pragma unroll
    for (int ni = 0; ni < 4; ++ni) bfr[ni] = *(const short8*)&Bs[(bcL + ni * 16) * 32 + kq];
#pragma unroll
    for (int mi = 0; mi < 4; ++mi) {
#pragma unroll
      for (int ni = 0; ni < 4; ++ni) {
        acc[mi][ni] = __builtin_amdgcn_mfma_f32_16x16x32_bf16(
            __builtin_bit_cast(bf16x8, af[mi]), __builtin_bit_cast(bf16x8, bfr[ni]),
            acc[mi][ni], 0, 0, 0);
      }
    }
  }

  // C/D layout: col=lane&15, row=(lane>>4)*4+reg
  const int er = (lane >> 4) << 2;
  const int ec = lane & 15;
  if constexpr (FUSE_DOT) {
    float g[4];
#pragma unroll
    for (int ni = 0; ni < 4; ++ni) {
      const int col = n0 + wn * 64 + ni * 16 + ec;
      g[ni] = w03[col] * wc3[cl * N + col];
    }
#pragma unroll
    for (int mi = 0; mi < 4; ++mi) {
#pragma unroll
      for (int r = 0; r < 4; ++r) {
        float v = 0.f;
#pragma unroll
        for (int ni = 0; ni < 4; ++ni) v += fmaxf(acc[mi][ni][r], 0.f) * g[ni];
#pragma unroll
        for (int m = 1; m < 16; m <<= 1) v += __shfl_xor(v, m);
        if ((lane & 15) == 0)
          atomicAdd(&z[row0 + wm * 64 + mi * 16 + er + r], v);
      }
    }
  } else {
#pragma unroll
    for (int mi = 0; mi < 4; ++mi) {
#pragma unroll
      for (int ni = 0; ni < 4; ++ni) {
#pragma unroll
        for (int r = 0; r < 4; ++r) {
          float vv = fmaxf(acc[mi][ni][r], 0.f);
          const int row = row0 + wm * 64 + mi * 16 + er + r;
          const int col = n0 + wn * 64 + ni * 16 + ec;
          Aout[(size_t)row * N + col] = f2bf(vv);
        }
      }
    }
  }
}

// sigmoid + scatter to original sample slots
__global__ void final_kernel(const float* __restrict__ z, const int* __restrict__ order,
                             const int* __restrict__ meta, float* __restrict__ out) {
  const int r = blockIdx.x * 256 + threadIdx.x;
  if (r < meta[1]) out[order[r]] = 1.f / (1.f + expf(-z[r]));
}

// -------- fallback GEMM (round-1): gating fused in staging, fp32 weights --------
template <int K, int N, bool GATHER>
__global__ void gemm_layer(const float* __restrict__ Xf, const short* __restrict__ Ain,
                           const float* __restrict__ w0, const float* __restrict__ wc,
                           short* __restrict__ Aout,
                           const int* __restrict__ order,
                           const int* __restrict__ tile_c, const int* __restrict__ tile_r,
                           const int* __restrict__ meta) {
  const int bt = blockIdx.x;
  if (bt >= meta[0]) return;
  const int cl = tile_c[bt];
  const int row0 = tile_r[bt];
  const int n0 = blockIdx.y * 128;

  __shared__ __align__(16) short As[128 * 40];
  __shared__ __align__(16) short Bs[128 * 40];

  const int tid = threadIdx.x;
  const int lane = tid & 63;
  const int wm = (tid >> 6) >> 1;
  const int wn = (tid >> 6) & 1;

  f32x4 acc[4][4] = {};

  const int arow = tid >> 2;
  const int akseg = (tid & 3) << 3;
  const int bn = tid & 127;
  const int bkq = (tid >> 7) << 3;

  const float* xr0 = nullptr; const float* xr1 = nullptr;
  const short* ar0 = nullptr; const short* ar1 = nullptr;
  if (GATHER) {
    xr0 = Xf + (size_t)order[row0 + arow] * K + akseg;
    xr1 = Xf + (size_t)order[row0 + arow + 64] * K + akseg;
  } else {
    ar0 = Ain + (size_t)(row0 + arow) * K + akseg;
    ar1 = Ain + (size_t)(row0 + arow + 64) * K + akseg;
  }
  const float* w0p = w0 + n0 + bn;
  const float* wcp = wc + (size_t)cl * K * N + n0 + bn;

  for (int kb = 0; kb < K; kb += 32) {
    __syncthreads();
    if (GATHER) {
      float4 a = *(const float4*)(xr0 + kb);
      float4 b = *(const float4*)(xr0 + kb + 4);
      short8 v;
      v[0] = f2bf(a.x); v[1] = f2bf(a.y); v[2] = f2bf(a.z); v[3] = f2bf(a.w);
      v[4] = f2bf(b.x); v[5] = f2bf(b.y); v[6] = f2bf(b.z); v[7] = f2bf(b.w);
      *(short8*)&As[arow * 40 + akseg] = v;
      a = *(const float4*)(xr1 + kb);
      b = *(const float4*)(xr1 + kb + 4);
      v[0] = f2bf(a.x); v[1] = f2bf(a.y); v[2] = f2bf(a.z); v[3] = f2bf(a.w);
      v[4] = f2bf(b.x); v[5] = f2bf(b.y); v[6] = f2bf(b.z); v[7] = f2bf(b.w);
      *(short8*)&As[(arow + 64) * 40 + akseg] = v;
    } else {
      *(short8*)&As[arow * 40 + akseg] = *(const short8*)(ar0 + kb);
      *(short8*)&As[(arow + 64) * 40 + akseg] = *(const short8*)(ar1 + kb);
    }
#pragma unroll
    for (int half = 0; half < 2; ++half) {
      const int kk = bkq + half * 16;
      short8 v;
#pragma unroll
      for (int j = 0; j < 8; ++j) {
        const size_t off = (size_t)(kb + kk + j) * N;
        v[j] = f2bf(w0p[off] * wcp[off]);
      }
      *(short8*)&Bs[bn * 40 + kk] = v;
    }
    __syncthreads();

    const int arL = wm * 64 + (lane & 15);
    const int kq = (lane >> 4) << 3;
    const int bcL = wn * 64 + (lane & 15);
    short8 af[4], bfr[4];
#pragma unroll
    for (int mi = 0; mi < 4; ++mi) af[mi] = *(const short8*)&As[(arL + mi * 16) * 40 + kq];
#pragma unroll
    for (int ni = 0; ni < 4; ++ni) bfr[ni] = *(const short8*)&Bs[(bcL + ni * 16) * 40 + kq];
#pragma unroll
    for (int mi = 0; mi < 4; ++mi) {
#pragma unroll
      for (int ni = 0; ni < 4; ++ni) {
        acc[mi][ni] = __builtin_amdgcn_mfma_f32_16x16x32_bf16(
            __builtin_bit_cast(bf16x8, af[mi]), __builtin_bit_cast(bf16x8, bfr[ni]),
            acc[mi][ni], 0, 0, 0);
      }
    }
  }

  const int er = (lane >> 4) << 2;
  const int ec = lane & 15;
#pragma unroll
  for (int mi = 0; mi < 4; ++mi) {
#pragma unroll
    for (int ni = 0; ni < 4; ++ni) {
#pragma unroll
      for (int r = 0; r < 4; ++r) {
        float vv = fmaxf(acc[mi][ni][r], 0.f);
        const int row = row0 + wm * 64 + mi * 16 + er + r;
        const int col = n0 + wn * 64 + ni * 16 + ec;
        Aout[(size_t)row * N + col] = f2bf(vv);
      }
    }
  }
}

// fallback final layer (reads h2 bf16)
__global__ void layer3_kernel(const short* __restrict__ h2, const float* __restrict__ w03,
                              const float* __restrict__ wc3, const int* __restrict__ order,
                              const int* __restrict__ pstart, const int* __restrict__ meta,
                              float* __restrict__ out) {
  const int tid = threadIdx.x;
  const int lane = tid & 63;
  const int w = tid >> 6;
  const int r = blockIdx.x * 4 + w;
  if (r >= meta[1]) return;
  int c = 0;
#pragma unroll
  for (int i = 1; i < CLN; ++i) { if (r >= pstart[i]) c = i; }
  const short* hr = h2 + (size_t)r * 512;
  const int k0 = lane * 8;
  const short8 hv = *(const short8*)(hr + k0);
  const float* wcr = wc3 + c * 512;
  float part = 0.f;
#pragma unroll
  for (int j = 0; j < 8; ++j) part += bf2f(hv[j]) * w03[k0 + j] * wcr[k0 + j];
  for (int off = 32; off; off >>= 1) part += __shfl_down(part, off);
  if (lane == 0) out[order[r]] = 1.f / (1.f + expf(-part));
}

extern "C" void kernel_launch(void* const* d_in, const int* in_sizes, int n_in,
                              void* d_out, int out_size, void* d_ws, size_t ws_size,
                              hipStream_t stream) {
  const float* x = (const float*)d_in[0];
  const float* center = (const float*)d_in[1];
  const float* w0s[4]; const float* wcs[4];
  if (in_sizes[3] == 8 * in_sizes[2]) {  // dict order: w0_i, wc_i interleaved
    for (int i = 0; i < 4; ++i) { w0s[i] = (const float*)d_in[2 + 2 * i]; wcs[i] = (const float*)d_in[3 + 2 * i]; }
  } else {                               // signature order: w0_0..w0_3, wc_0..wc_3
    for (int i = 0; i < 4; ++i) { w0s[i] = (const float*)d_in[2 + i]; wcs[i] = (const float*)d_in[6 + i]; }
  }
  float* out = (float*)d_out;
  char* ws = (char*)d_ws;
  int* counts = (int*)(ws + 0);      // 8
  int* pstart = (int*)(ws + 128);    // 9
  int* meta   = (int*)(ws + 192);    // 2
  int* tile_c = (int*)(ws + 256);    // 72
  int* tile_r = (int*)(ws + 1024);   // 72
  int* router = (int*)(ws + 4096);   // 8192 ints
  int* order  = (int*)(ws + 4096 + 4 * B_SZ);         // 9216 ints
  float* z    = (float*)(ws + 4096 + 4 * B_SZ + 4 * PADMAX);  // 9216 floats, ends < 131072

  const size_t GW0 = (size_t)CLN * 1024 * 2048 * 2;   // 33.55 MB
  const size_t GW1 = (size_t)CLN * 2048 * 1024 * 2;   // 33.55 MB
  const size_t GW2 = (size_t)CLN * 1024 * 512 * 2;    // 8.39 MB
  const size_t H0B = (size_t)PADMAX * 2048 * 2;       // 37.75 MB
  const size_t H1B = (size_t)PADMAX * 1024 * 2;       // 18.87 MB (>= xb 16.8 MB)
  const size_t NEED_A = 131072 + GW0 + GW1 + GW2 + H0B + H1B;  // ~132 MB (proven fits)
  const size_t NEED_B = 131072 + GW1 + H0B + H1B;              // ~90 MB
  const int tier = (ws_size >= NEED_A) ? 0 : (ws_size >= NEED_B) ? 1 : 2;

  if (tier == 0) {
    short* gw0 = (short*)(ws + 131072);
    short* gw1 = (short*)(ws + 131072 + GW0);
    short* gw2 = (short*)(ws + 131072 + GW0 + GW1);
    short* h0  = (short*)(ws + 131072 + GW0 + GW1 + GW2);
    short* h1  = (short*)(ws + 131072 + GW0 + GW1 + GW2 + H0B);
    short* xb  = h1;   // xb lives prep->gemm0; h1 lives gemm1->gemm2 (disjoint)

    router_kernel<<<2048, 256, 0, stream>>>(x, center, router, xb);
    gate_kernel<<<4608, 256, 0, stream>>>(w0s[0], wcs[0], gw0,
                                          w0s[1], wcs[1], gw1,
                                          w0s[2], wcs[2], gw2);
    sort_kernel<<<1, 1024, 0, stream>>>(router, counts, pstart, meta, tile_c, tile_r, order, z);
    gemm_async<1024, 2048, true, false><<<MAX_TILES * 16, 256, 0, stream>>>(
        xb, gw0, h0, order, tile_c, tile_r, meta, nullptr, nullptr, nullptr);
    gemm_async<2048, 1024, false, false><<<MAX_TILES * 8, 256, 0, stream>>>(
        h0, gw1, h1, order, tile_c, tile_r, meta, nullptr, nullptr, nullptr);
    gemm_async<1024, 512, false, true><<<MAX_TILES * 4, 256, 0, stream>>>(
        h1, gw2, nullptr, order, tile_c, tile_r, meta, w0s[3], wcs[3], z);
    final_kernel<<<PADMAX / 256, 256, 0, stream>>>(z, order, meta, out);
  } else if (tier == 1) {
    short* gw = (short*)(ws + 131072);
    short* h0 = (short*)(ws + 131072 + GW1);
    short* h1 = (short*)(ws + 131072 + GW1 + H0B);
    short* xb = h1;

    router_kernel<<<2048, 256, 0, stream>>>(x, center, router, xb);
    sort_kernel<<<1, 1024, 0, stream>>>(router, counts, pstart, meta, tile_c, tile_r, order, z);
    gate1_kernel<1024, 2048><<<2048, 256, 0, stream>>>(w0s[0], wcs[0], gw);
    gemm_async<1024, 2048, true, false><<<MAX_TILES * 16, 256, 0, stream>>>(
        xb, gw, h0, order, tile_c, tile_r, meta, nullptr, nullptr, nullptr);
    gate1_kernel<2048, 1024><<<2048, 256, 0, stream>>>(w0s[1], wcs[1], gw);
    gemm_async<2048, 1024, false, false><<<MAX_TILES * 8, 256, 0, stream>>>(
        h0, gw, h1, order, tile_c, tile_r, meta, nullptr, nullptr, nullptr);
    gate1_kernel<1024, 512><<<512, 256, 0, stream>>>(w0s[2], wcs[2], gw);
    gemm_async<1024, 512, false, true><<<MAX_TILES * 4, 256, 0, stream>>>(
        h1, gw, nullptr, order, tile_c, tile_r, meta, w0s[3], wcs[3], z);
    final_kernel<<<PADMAX / 256, 256, 0, stream>>>(z, order, meta, out);
  } else {
    short* f0 = (short*)(ws + 131072);
    short* f1 = f0 + (size_t)PADMAX * 2048;
    short* f2 = f1 + (size_t)PADMAX * 1024;
    router_kernel<<<2048, 256, 0, stream>>>(x, center, router, nullptr);
    sort_kernel<<<1, 1024, 0, stream>>>(router, counts, pstart, meta, tile_c, tile_r, order, z);
    gemm_layer<1024, 2048, true><<<dim3(MAX_TILES, 16), 256, 0, stream>>>(
        x, nullptr, w0s[0], wcs[0], f0, order, tile_c, tile_r, meta);
    gemm_layer<2048, 1024, false><<<dim3(MAX_TILES, 8), 256, 0, stream>>>(
        nullptr, f0, w0s[1], wcs[1], f1, order, tile_c, tile_r, meta);
    gemm_layer<1024, 512, false><<<dim3(MAX_TILES, 4), 256, 0, stream>>>(
        nullptr, f1, w0s[2], wcs[2], f2, order, tile_c, tile_r, meta);
    layer3_kernel<<<(PADMAX + 3) / 4, 256, 0, stream>>>(f2, w0s[3], wcs[3], order, pstart, meta, out);
  }
}

// Round 4
// 407.217 us; speedup vs baseline: 1.0022x; 1.0022x over previous
//
#include <hip/hip_runtime.h>
#include <hip/hip_bf16.h>

#define B_SZ 8192
#define DIMS 1024
#define CLN 8
#define BM 128
#define PADMAX (B_SZ + CLN * BM)     // 9216
#define MAX_TILES (B_SZ / BM + CLN)  // 72

typedef __attribute__((ext_vector_type(8))) __bf16 bf16x8;
typedef __attribute__((ext_vector_type(8))) short short8;
typedef __attribute__((ext_vector_type(4))) short short4v;
typedef __attribute__((ext_vector_type(4))) float f32x4;

__device__ __forceinline__ short f2bf(float f) {
  __hip_bfloat16 h = __float2bfloat16(f);
  return __builtin_bit_cast(short, h);
}
__device__ __forceinline__ float bf2f(short s) {
  unsigned u = ((unsigned)(unsigned short)s) << 16;
  return __builtin_bit_cast(float, u);
}

// async 16B/lane global->LDS DMA. LDS dest is wave-uniform base; HW adds lane*16.
__device__ __forceinline__ void gl_lds16(const short* g, short* l) {
  __builtin_amdgcn_global_load_lds(
      (const __attribute__((address_space(1))) unsigned int*)(unsigned long long)(uintptr_t)g,
      (__attribute__((address_space(3))) unsigned int*)(unsigned long long)(uintptr_t)l,
      16, 0, 0);
}

// ---- router body: 4 waves/block, 1 sample/wave, fused fp32->bf16 of x ----
// Round-8: center loads batched 8-wide per j-chunk (old form held one cv
// float4 in flight -> L2-latency chain at 36 VGPRs).
__device__ __forceinline__ void router_body(const float* __restrict__ x,
                                            const float* __restrict__ center,
                                            int* __restrict__ router, short* __restrict__ xb,
                                            int bx) {
  const int tid = threadIdx.x;
  const int lane = tid & 63;
  const int w = tid >> 6;
  const int s = bx * 4 + w;
  const float4* xr = (const float4*)(x + (size_t)s * DIMS);
  float4 xv[4];
#pragma unroll
  for (int j = 0; j < 4; ++j) xv[j] = xr[j * 64 + lane];
  if (xb) {
    short* xbr = xb + (size_t)s * DIMS;
#pragma unroll
    for (int j = 0; j < 4; ++j) {
      short4v sv;
      sv[0] = f2bf(xv[j].x); sv[1] = f2bf(xv[j].y);
      sv[2] = f2bf(xv[j].z); sv[3] = f2bf(xv[j].w);
      *(short4v*)(xbr + j * 256 + lane * 4) = sv;
    }
  }
  float p[CLN];
#pragma unroll
  for (int c = 0; c < CLN; ++c) p[c] = 0.f;
#pragma unroll
  for (int j = 0; j < 4; ++j) {
    float4 cv[CLN];
#pragma unroll
    for (int c = 0; c < CLN; ++c)
      cv[c] = ((const float4*)(center + (size_t)c * DIMS))[j * 64 + lane];
#pragma unroll
    for (int c = 0; c < CLN; ++c)
      p[c] += xv[j].x * cv[c].x + xv[j].y * cv[c].y + xv[j].z * cv[c].z + xv[j].w * cv[c].w;
  }
#pragma unroll
  for (int c = 0; c < CLN; ++c) {
#pragma unroll
    for (int m = 1; m < 64; m <<= 1) p[c] += __shfl_xor(p[c], m);
  }
  if (lane == 0) {
    int best = 0; float bv = p[0];
#pragma unroll
    for (int c = 1; c < CLN; ++c) { if (p[c] > bv) { bv = p[c]; best = c; } }
    router[s] = best;
  }
}

// ---- gate body: gwt[c][n][k] = bf16(w0[k][n]*wc[c][k][n]) ----
// 128k x 64n tile per block, n0-fastest block order.
// Round-8 root cause of the 2.1 TB/s invariant: hipcc allocated 40 VGPRs
// (chasing 8 waves/SIMD) vs the 64 needed to keep a[8]+b[8] live -> loads
// serialized, ~2 in flight/thread, latency-bound. Kernel-level
// __launch_bounds__(256,4) raises the budget to 128 so all 16 dwordx4
// loads stay outstanding. Measured occupancy was 50% (4 waves/SIMD)
// anyway, so nothing is lost.
template <int K, int N>
__device__ __forceinline__ void gate_body(const float* __restrict__ w0,
                                          const float* __restrict__ wc,
                                          short* __restrict__ gwt, int bx, short* lds) {
  constexpr int KB = K / 128, NB = N / 64;
  const int c = bx / (KB * NB);
  const int rem = bx % (KB * NB);
  const int k0 = (rem / NB) * 128;   // k slowest
  const int n0 = (rem % NB) * 64;    // n fastest
  const int tid = threadIdx.x;
  // phase 1: thread (i = tid&15 -> n-quad, q = tid>>4 -> k-octet) loads 8 rows x float4
  const int i = tid & 15;
  const int q = tid >> 4;
  const float* w0p = w0 + (size_t)(k0 + q * 8) * N + n0 + i * 4;
  const float* wcp = wc + ((size_t)c * K + k0 + q * 8) * N + n0 + i * 4;
  float4 a[8], b[8];
#pragma unroll
  for (int j = 0; j < 8; ++j) {
    a[j] = *(const float4*)(w0p + (size_t)j * N);
    b[j] = *(const float4*)(wcp + (size_t)j * N);
  }
#pragma unroll
  for (int jj = 0; jj < 4; ++jj) {
    const int r = i * 4 + jj;        // n-row within tile
    short8 v;
#pragma unroll
    for (int j = 0; j < 8; ++j) {
      const float* af = (const float*)&a[j];
      const float* bf = (const float*)&b[j];
      v[j] = f2bf(af[jj] * bf[jj]);
    }
    const int sw = q ^ (r & 15);     // swizzled col-block
    *(short8*)&lds[r * 128 + sw * 8] = v;
  }
  __syncthreads();
  // phase 2: thread (n = tid>>2, seg = tid&3) reads 32 shorts, stores 64 B
  const int n = tid >> 2;
  const int seg = tid & 3;
  short8 rv[4];
#pragma unroll
  for (int u = 0; u < 4; ++u) {
    const int cb = seg * 4 + u;
    const int sw = cb ^ (n & 15);
    rv[u] = *(const short8*)&lds[n * 128 + sw * 8];
  }
  short* dst = gwt + ((size_t)c * N + n0 + n) * K + k0 + seg * 32;
#pragma unroll
  for (int u = 0; u < 4; ++u) *(short8*)(dst + u * 8) = rv[u];
}

// ---- fused prep: router blocks + all three gate layers (overlap + 1 launch) ----
// L0: 8*32*8=2048, L1: 16*16*8=2048, L2: 8*8*8=512 gate blocks (4608 total).
__global__ void __launch_bounds__(256, 4)
prep_kernel(const float* __restrict__ x, const float* __restrict__ center,
            int* __restrict__ router, short* __restrict__ xb,
            const float* w00, const float* wc0, short* g0,
            const float* w01, const float* wc1, short* g1,
            const float* w02, const float* wc2, short* g2) {
  __shared__ short lds[64 * 128];
  const int bx = blockIdx.x;
  if (bx < 2048) { router_body(x, center, router, xb, bx); return; }
  const int gx = bx - 2048;
  if (gx < 2048)       gate_body<1024, 2048>(w00, wc0, g0, gx, lds);
  else if (gx < 4096)  gate_body<2048, 1024>(w01, wc1, g1, gx - 2048, lds);
  else                 gate_body<1024, 512>(w02, wc2, g2, gx - 4096, lds);
}

// tier-1/2 standalone router
__global__ void __launch_bounds__(256, 4)
router_kernel(const float* __restrict__ x, const float* __restrict__ center,
              int* __restrict__ router, short* __restrict__ xb) {
  router_body(x, center, router, xb, blockIdx.x);
}

// tier-1 single-layer gate
template <int K, int N>
__global__ void __launch_bounds__(256, 4)
gate1_kernel(const float* __restrict__ w0, const float* __restrict__ wc,
             short* __restrict__ gwt) {
  __shared__ short lds[64 * 128];
  gate_body<K, N>(w0, wc, gwt, blockIdx.x, lds);
}

// ---- mono-block counting sort + zero z ----
__global__ void sort_kernel(const int* __restrict__ router, int* __restrict__ counts,
                            int* __restrict__ pstart, int* __restrict__ meta,
                            int* __restrict__ tile_c, int* __restrict__ tile_r,
                            int* __restrict__ order, float* __restrict__ z) {
  __shared__ int bins[CLN];
  __shared__ int cur[CLN];
  __shared__ int ps_s[CLN + 1];
  const int t = threadIdx.x;
  const int lane = t & 63;
  for (int p = t; p < PADMAX; p += 1024) z[p] = 0.f;   // gemm2 dot-accumulator
  if (t < CLN) bins[t] = 0;
  __syncthreads();
  int myc[8];
#pragma unroll
  for (int j = 0; j < 8; ++j) myc[j] = router[t + 1024 * j];
#pragma unroll
  for (int j = 0; j < 8; ++j) {
#pragma unroll
    for (int c = 0; c < CLN; ++c) {
      unsigned long long m = __ballot(myc[j] == c);
      if (lane == 0 && m) atomicAdd(&bins[c], __popcll(m));
    }
  }
  __syncthreads();
  if (t == 0) {
    int ps = 0, nt = 0;
    for (int c = 0; c < CLN; ++c) {
      const int tot = bins[c];
      counts[c] = tot; pstart[c] = ps; ps_s[c] = ps; cur[c] = 0;
      const int tiles = (tot + BM - 1) / BM;
      for (int i = 0; i < tiles; ++i) { tile_c[nt] = c; tile_r[nt] = ps + i * BM; ++nt; }
      ps += tiles * BM;
    }
    pstart[CLN] = ps; ps_s[CLN] = ps; meta[0] = nt; meta[1] = ps;
  }
  __syncthreads();
#pragma unroll
  for (int j = 0; j < 8; ++j) {
    const int s = t + 1024 * j;
    const int c = myc[j];
    int pos = 0;
#pragma unroll
    for (int cc = 0; cc < CLN; ++cc) {
      unsigned long long m = __ballot(c == cc);
      int b = 0;
      if (lane == 0 && m) b = atomicAdd(&cur[cc], __popcll(m));
      b = __shfl(b, 0);
      if (c == cc) pos = ps_s[cc] + b + __popcll(m & ((1ull << lane) - 1ull));
    }
    order[pos] = s;
  }
  __syncthreads();
  for (int p = t; p < PADMAX; p += 1024) {
#pragma unroll
    for (int c = 0; c < CLN; ++c) {
      if (p >= ps_s[c] && p < ps_s[c + 1]) {
        if (p - ps_s[c] >= bins[c]) order[p] = order[ps_s[c]];
        break;
      }
    }
  }
}

// -------- GEMM: BK=32 (round-4-measured), global_load_lds(16B), bf16 --------
// 128x128 tile, 4 waves (2x2 of 64x64), mfma_f32_16x16x32_bf16.
// 1-D grid, n0 fastest: B-slice sharers (stride NT = 0 mod 8) pin to one XCD.
// FUSE_DOT (layer 2): epilogue computes gated w3 dot per row + atomicAdd to z
// instead of writing h2 (saves 19 MB write + re-read + a kernel).
template <int K, int N, bool GATHER, bool FUSE_DOT>
__global__ void gemm_async(const short* __restrict__ Abase, const short* __restrict__ gwt,
                           short* __restrict__ Aout, const int* __restrict__ order,
                           const int* __restrict__ tile_c, const int* __restrict__ tile_r,
                           const int* __restrict__ meta,
                           const float* __restrict__ w03, const float* __restrict__ wc3,
                           float* __restrict__ z) {
  constexpr int NT = N / 128;
  const int bt = blockIdx.x / NT;
  if (bt >= meta[0]) return;
  const int n0 = (blockIdx.x % NT) * 128;
  const int cl = tile_c[bt];
  const int row0 = tile_r[bt];

  __shared__ __align__(16) short As[128 * 32];
  __shared__ __align__(16) short Bs[128 * 32];  // Bs[n][k]

  const int tid = threadIdx.x;
  const int lane = tid & 63;
  const int w = tid >> 6;
  const int wm = w >> 1;
  const int wn = w & 1;

  const int lrow = lane >> 2;
  const int kofs = (lane & 3) << 3;
  const short* ga0;
  const short* ga1;
  if (GATHER) {
    ga0 = Abase + (size_t)order[row0 + w * 16 + lrow] * K + kofs;
    ga1 = Abase + (size_t)order[row0 + 64 + w * 16 + lrow] * K + kofs;
  } else {
    ga0 = Abase + (size_t)(row0 + w * 16 + lrow) * K + kofs;
    ga1 = ga0 + (size_t)64 * K;
  }
  const short* gb0 = gwt + ((size_t)cl * N + n0 + w * 16 + lrow) * K + kofs;
  const short* gb1 = gb0 + (size_t)64 * K;
  short* lA0 = &As[w * 16 * 32];
  short* lA1 = &As[(64 + w * 16) * 32];
  short* lB0 = &Bs[w * 16 * 32];
  short* lB1 = &Bs[(64 + w * 16) * 32];

  f32x4 acc[4][4] = {};
  const int arL = wm * 64 + (lane & 15);
  const int bcL = wn * 64 + (lane & 15);
  const int kq = (lane >> 4) << 3;

  for (int kb = 0; kb < K; kb += 32) {
    __syncthreads();
    gl_lds16(ga0 + kb, lA0);
    gl_lds16(ga1 + kb, lA1);
    gl_lds16(gb0 + kb, lB0);
    gl_lds16(gb1 + kb, lB1);
    __syncthreads();

    short8 af[4], bfr[4];
#pragma unroll
    for (int mi = 0; mi < 4; ++mi) af[mi] = *(const short8*)&As[(arL + mi * 16) * 32 + kq];
#pragma unroll
    for (int ni = 0; ni < 4; ++ni) bfr[ni] = *(const short8*)&Bs[(bcL + ni * 16) * 32 + kq];
#pragma unroll
    for (int mi = 0; mi < 4; ++mi) {
#pragma unroll
      for (int ni = 0; ni < 4; ++ni) {
        acc[mi][ni] = __builtin_amdgcn_mfma_f32_16x16x32_bf16(
            __builtin_bit_cast(bf16x8, af[mi]), __builtin_bit_cast(bf16x8, bfr[ni]),
            acc[mi][ni], 0, 0, 0);
      }
    }
  }

  // C/D layout: col=lane&15, row=(lane>>4)*4+reg
  const int er = (lane >> 4) << 2;
  const int ec = lane & 15;
  if constexpr (FUSE_DOT) {
    float g[4];
#pragma unroll
    for (int ni = 0; ni < 4; ++ni) {
      const int col = n0 + wn * 64 + ni * 16 + ec;
      g[ni] = w03[col] * wc3[cl * N + col];
    }
#pragma unroll
    for (int mi = 0; mi < 4; ++mi) {
#pragma unroll
      for (int r = 0; r < 4; ++r) {
        float v = 0.f;
#pragma unroll
        for (int ni = 0; ni < 4; ++ni) v += fmaxf(acc[mi][ni][r], 0.f) * g[ni];
#pragma unroll
        for (int m = 1; m < 16; m <<= 1) v += __shfl_xor(v, m);
        if ((lane & 15) == 0)
          atomicAdd(&z[row0 + wm * 64 + mi * 16 + er + r], v);
      }
    }
  } else {
#pragma unroll
    for (int mi = 0; mi < 4; ++mi) {
#pragma unroll
      for (int ni = 0; ni < 4; ++ni) {
#pragma unroll
        for (int r = 0; r < 4; ++r) {
          float vv = fmaxf(acc[mi][ni][r], 0.f);
          const int row = row0 + wm * 64 + mi * 16 + er + r;
          const int col = n0 + wn * 64 + ni * 16 + ec;
          Aout[(size_t)row * N + col] = f2bf(vv);
        }
      }
    }
  }
}

// sigmoid + scatter to original sample slots
__global__ void final_kernel(const float* __restrict__ z, const int* __restrict__ order,
                             const int* __restrict__ meta, float* __restrict__ out) {
  const int r = blockIdx.x * 256 + threadIdx.x;
  if (r < meta[1]) out[order[r]] = 1.f / (1.f + expf(-z[r]));
}

// -------- fallback GEMM (round-1): gating fused in staging, fp32 weights --------
template <int K, int N, bool GATHER>
__global__ void gemm_layer(const float* __restrict__ Xf, const short* __restrict__ Ain,
                           const float* __restrict__ w0, const float* __restrict__ wc,
                           short* __restrict__ Aout,
                           const int* __restrict__ order,
                           const int* __restrict__ tile_c, const int* __restrict__ tile_r,
                           const int* __restrict__ meta) {
  const int bt = blockIdx.x;
  if (bt >= meta[0]) return;
  const int cl = tile_c[bt];
  const int row0 = tile_r[bt];
  const int n0 = blockIdx.y * 128;

  __shared__ __align__(16) short As[128 * 40];
  __shared__ __align__(16) short Bs[128 * 40];

  const int tid = threadIdx.x;
  const int lane = tid & 63;
  const int wm = (tid >> 6) >> 1;
  const int wn = (tid >> 6) & 1;

  f32x4 acc[4][4] = {};

  const int arow = tid >> 2;
  const int akseg = (tid & 3) << 3;
  const int bn = tid & 127;
  const int bkq = (tid >> 7) << 3;

  const float* xr0 = nullptr; const float* xr1 = nullptr;
  const short* ar0 = nullptr; const short* ar1 = nullptr;
  if (GATHER) {
    xr0 = Xf + (size_t)order[row0 + arow] * K + akseg;
    xr1 = Xf + (size_t)order[row0 + arow + 64] * K + akseg;
  } else {
    ar0 = Ain + (size_t)(row0 + arow) * K + akseg;
    ar1 = Ain + (size_t)(row0 + arow + 64) * K + akseg;
  }
  const float* w0p = w0 + n0 + bn;
  const float* wcp = wc + (size_t)cl * K * N + n0 + bn;

  for (int kb = 0; kb < K; kb += 32) {
    __syncthreads();
    if (GATHER) {
      float4 a = *(const float4*)(xr0 + kb);
      float4 b = *(const float4*)(xr0 + kb + 4);
      short8 v;
      v[0] = f2bf(a.x); v[1] = f2bf(a.y); v[2] = f2bf(a.z); v[3] = f2bf(a.w);
      v[4] = f2bf(b.x); v[5] = f2bf(b.y); v[6] = f2bf(b.z); v[7] = f2bf(b.w);
      *(short8*)&As[arow * 40 + akseg] = v;
      a = *(const float4*)(xr1 + kb);
      b = *(const float4*)(xr1 + kb + 4);
      v[0] = f2bf(a.x); v[1] = f2bf(a.y); v[2] = f2bf(a.z); v[3] = f2bf(a.w);
      v[4] = f2bf(b.x); v[5] = f2bf(b.y); v[6] = f2bf(b.z); v[7] = f2bf(b.w);
      *(short8*)&As[(arow + 64) * 40 + akseg] = v;
    } else {
      *(short8*)&As[arow * 40 + akseg] = *(const short8*)(ar0 + kb);
      *(short8*)&As[(arow + 64) * 40 + akseg] = *(const short8*)(ar1 + kb);
    }
#pragma unroll
    for (int half = 0; half < 2; ++half) {
      const int kk = bkq + half * 16;
      short8 v;
#pragma unroll
      for (int j = 0; j < 8; ++j) {
        const size_t off = (size_t)(kb + kk + j) * N;
        v[j] = f2bf(w0p[off] * wcp[off]);
      }
      *(short8*)&Bs[bn * 40 + kk] = v;
    }
    __syncthreads();

    const int arL = wm * 64 + (lane & 15);
    const int kq = (lane >> 4) << 3;
    const int bcL = wn * 64 + (lane & 15);
    short8 af[4], bfr[4];
#pragma unroll
    for (int mi = 0; mi < 4; ++mi) af[mi] = *(const short8*)&As[(arL + mi * 16) * 40 + kq];
#pragma unroll
    for (int ni = 0; ni < 4; ++ni) bfr[ni] = *(const short8*)&Bs[(bcL + ni * 16) * 40 + kq];
#pragma unroll
    for (int mi = 0; mi < 4; ++mi) {
#pragma unroll
      for (int ni = 0; ni < 4; ++ni) {
        acc[mi][ni] = __builtin_amdgcn_mfma_f32_16x16x32_bf16(
            __builtin_bit_cast(bf16x8, af[mi]), __builtin_bit_cast(bf16x8, bfr[ni]),
            acc[mi][ni], 0, 0, 0);
      }
    }
  }

  const int er = (lane >> 4) << 2;
  const int ec = lane & 15;
#pragma unroll
  for (int mi = 0; mi < 4; ++mi) {
#pragma unroll
    for (int ni = 0; ni < 4; ++ni) {
#pragma unroll
      for (int r = 0; r < 4; ++r) {
        float vv = fmaxf(acc[mi][ni][r], 0.f);
        const int row = row0 + wm * 64 + mi * 16 + er + r;
        const int col = n0 + wn * 64 + ni * 16 + ec;
        Aout[(size_t)row * N + col] = f2bf(vv);
      }
    }
  }
}

// fallback final layer (reads h2 bf16)
__global__ void layer3_kernel(const short* __restrict__ h2, const float* __restrict__ w03,
                              const float* __restrict__ wc3, const int* __restrict__ order,
                              const int* __restrict__ pstart, const int* __restrict__ meta,
                              float* __restrict__ out) {
  const int tid = threadIdx.x;
  const int lane = tid & 63;
  const int w = tid >> 6;
  const int r = blockIdx.x * 4 + w;
  if (r >= meta[1]) return;
  int c = 0;
#pragma unroll
  for (int i = 1; i < CLN; ++i) { if (r >= pstart[i]) c = i; }
  const short* hr = h2 + (size_t)r * 512;
  const int k0 = lane * 8;
  const short8 hv = *(const short8*)(hr + k0);
  const float* wcr = wc3 + c * 512;
  float part = 0.f;
#pragma unroll
  for (int j = 0; j < 8; ++j) part += bf2f(hv[j]) * w03[k0 + j] * wcr[k0 + j];
  for (int off = 32; off; off >>= 1) part += __shfl_down(part, off);
  if (lane == 0) out[order[r]] = 1.f / (1.f + expf(-part));
}

extern "C" void kernel_launch(void* const* d_in, const int* in_sizes, int n_in,
                              void* d_out, int out_size, void* d_ws, size_t ws_size,
                              hipStream_t stream) {
  const float* x = (const float*)d_in[0];
  const float* center = (const float*)d_in[1];
  const float* w0s[4]; const float* wcs[4];
  if (in_sizes[3] == 8 * in_sizes[2]) {  // dict order: w0_i, wc_i interleaved
    for (int i = 0; i < 4; ++i) { w0s[i] = (const float*)d_in[2 + 2 * i]; wcs[i] = (const float*)d_in[3 + 2 * i]; }
  } else {                               // signature order: w0_0..w0_3, wc_0..wc_3
    for (int i = 0; i < 4; ++i) { w0s[i] = (const float*)d_in[2 + i]; wcs[i] = (const float*)d_in[6 + i]; }
  }
  float* out = (float*)d_out;
  char* ws = (char*)d_ws;
  int* counts = (int*)(ws + 0);      // 8
  int* pstart = (int*)(ws + 128);    // 9
  int* meta   = (int*)(ws + 192);    // 2
  int* tile_c = (int*)(ws + 256);    // 72
  int* tile_r = (int*)(ws + 1024);   // 72
  int* router = (int*)(ws + 4096);   // 8192 ints
  int* order  = (int*)(ws + 4096 + 4 * B_SZ);         // 9216 ints
  float* z    = (float*)(ws + 4096 + 4 * B_SZ + 4 * PADMAX);  // 9216 floats, ends < 131072

  const size_t GW0 = (size_t)CLN * 1024 * 2048 * 2;   // 33.55 MB
  const size_t GW1 = (size_t)CLN * 2048 * 1024 * 2;   // 33.55 MB
  const size_t GW2 = (size_t)CLN * 1024 * 512 * 2;    // 8.39 MB
  const size_t H0B = (size_t)PADMAX * 2048 * 2;       // 37.75 MB
  const size_t H1B = (size_t)PADMAX * 1024 * 2;       // 18.87 MB (>= xb 16.8 MB)
  const size_t NEED_A = 131072 + GW0 + GW1 + GW2 + H0B + H1B;  // ~132 MB (proven fits)
  const size_t NEED_B = 131072 + GW1 + H0B + H1B;              // ~90 MB
  const int tier = (ws_size >= NEED_A) ? 0 : (ws_size >= NEED_B) ? 1 : 2;

  if (tier == 0) {
    short* gw0 = (short*)(ws + 131072);
    short* gw1 = (short*)(ws + 131072 + GW0);
    short* gw2 = (short*)(ws + 131072 + GW0 + GW1);
    short* h0  = (short*)(ws + 131072 + GW0 + GW1 + GW2);
    short* h1  = (short*)(ws + 131072 + GW0 + GW1 + GW2 + H0B);
    short* xb  = h1;   // xb lives prep->gemm0; h1 lives gemm1->gemm2 (disjoint)

    prep_kernel<<<2048 + 4608, 256, 0, stream>>>(x, center, router, xb,
                                                 w0s[0], wcs[0], gw0,
                                                 w0s[1], wcs[1], gw1,
                                                 w0s[2], wcs[2], gw2);
    sort_kernel<<<1, 1024, 0, stream>>>(router, counts, pstart, meta, tile_c, tile_r, order, z);
    gemm_async<1024, 2048, true, false><<<MAX_TILES * 16, 256, 0, stream>>>(
        xb, gw0, h0, order, tile_c, tile_r, meta, nullptr, nullptr, nullptr);
    gemm_async<2048, 1024, false, false><<<MAX_TILES * 8, 256, 0, stream>>>(
        h0, gw1, h1, order, tile_c, tile_r, meta, nullptr, nullptr, nullptr);
    gemm_async<1024, 512, false, true><<<MAX_TILES * 4, 256, 0, stream>>>(
        h1, gw2, nullptr, order, tile_c, tile_r, meta, w0s[3], wcs[3], z);
    final_kernel<<<PADMAX / 256, 256, 0, stream>>>(z, order, meta, out);
  } else if (tier == 1) {
    short* gw = (short*)(ws + 131072);
    short* h0 = (short*)(ws + 131072 + GW1);
    short* h1 = (short*)(ws + 131072 + GW1 + H0B);
    short* xb = h1;

    router_kernel<<<2048, 256, 0, stream>>>(x, center, router, xb);
    sort_kernel<<<1, 1024, 0, stream>>>(router, counts, pstart, meta, tile_c, tile_r, order, z);
    gate1_kernel<1024, 2048><<<2048, 256, 0, stream>>>(w0s[0], wcs[0], gw);
    gemm_async<1024, 2048, true, false><<<MAX_TILES * 16, 256, 0, stream>>>(
        xb, gw, h0, order, tile_c, tile_r, meta, nullptr, nullptr, nullptr);
    gate1_kernel<2048, 1024><<<2048, 256, 0, stream>>>(w0s[1], wcs[1], gw);
    gemm_async<2048, 1024, false, false><<<MAX_TILES * 8, 256, 0, stream>>>(
        h0, gw, h1, order, tile_c, tile_r, meta, nullptr, nullptr, nullptr);
    gate1_kernel<1024, 512><<<512, 256, 0, stream>>>(w0s[2], wcs[2], gw);
    gemm_async<1024, 512, false, true><<<MAX_TILES * 4, 256, 0, stream>>>(
        h1, gw, nullptr, order, tile_c, tile_r, meta, w0s[3], wcs[3], z);
    final_kernel<<<PADMAX / 256, 256, 0, stream>>>(z, order, meta, out);
  } else {
    short* f0 = (short*)(ws + 131072);
    short* f1 = f0 + (size_t)PADMAX * 2048;
    short* f2 = f1 + (size_t)PADMAX * 1024;
    router_kernel<<<2048, 256, 0, stream>>>(x, center, router, nullptr);
    sort_kernel<<<1, 1024, 0, stream>>>(router, counts, pstart, meta, tile_c, tile_r, order, z);
    gemm_layer<1024, 2048, true><<<dim3(MAX_TILES, 16), 256, 0, stream>>>(
        x, nullptr, w0s[0], wcs[0], f0, order, tile_c, tile_r, meta);
    gemm_layer<2048, 1024, false><<<dim3(MAX_TILES, 8), 256, 0, stream>>>(
        nullptr, f0, w0s[1], wcs[1], f1, order, tile_c, tile_r, meta);
    gemm_layer<1024, 512, false><<<dim3(MAX_TILES, 4), 256, 0, stream>>>(
        nullptr, f1, w0s[2], wcs[2], f2, order, tile_c, tile_r, meta);
    layer3_kernel<<<(PADMAX + 3) / 4, 256, 0, stream>>>(f2, w0s[3], wcs[3], order, pstart, meta, out);
  }
}

// Round 5
// 396.893 us; speedup vs baseline: 1.0282x; 1.0260x over previous
//
#include <hip/hip_runtime.h>
#include <hip/hip_bf16.h>

#define B_SZ 8192
#define DIMS 1024
#define CLN 8
#define BM 128
#define PADMAX (B_SZ + CLN * BM)     // 9216
#define MAX_TILES (B_SZ / BM + CLN)  // 72

typedef __attribute__((ext_vector_type(8))) __bf16 bf16x8;
typedef __attribute__((ext_vector_type(8))) short short8;
typedef __attribute__((ext_vector_type(4))) short short4v;
typedef __attribute__((ext_vector_type(4))) float f32x4;

__device__ __forceinline__ short f2bf(float f) {
  __hip_bfloat16 h = __float2bfloat16(f);
  return __builtin_bit_cast(short, h);
}
__device__ __forceinline__ float bf2f(short s) {
  unsigned u = ((unsigned)(unsigned short)s) << 16;
  return __builtin_bit_cast(float, u);
}

// async 16B/lane global->LDS DMA. LDS dest is wave-uniform base; HW adds lane*16.
__device__ __forceinline__ void gl_lds16(const void* g, void* l) {
  __builtin_amdgcn_global_load_lds(
      (const __attribute__((address_space(1))) unsigned int*)(unsigned long long)(uintptr_t)g,
      (__attribute__((address_space(3))) unsigned int*)(unsigned long long)(uintptr_t)l,
      16, 0, 0);
}

// ---- router body: 4 waves/block, 1 sample/wave, fused fp32->bf16 of x ----
__device__ __forceinline__ void router_body(const float* __restrict__ x,
                                            const float* __restrict__ center,
                                            int* __restrict__ router, short* __restrict__ xb,
                                            int bx) {
  const int tid = threadIdx.x;
  const int lane = tid & 63;
  const int w = tid >> 6;
  const int s = bx * 4 + w;
  const float4* xr = (const float4*)(x + (size_t)s * DIMS);
  float4 xv[4];
#pragma unroll
  for (int j = 0; j < 4; ++j) xv[j] = xr[j * 64 + lane];
  if (xb) {
    short* xbr = xb + (size_t)s * DIMS;
#pragma unroll
    for (int j = 0; j < 4; ++j) {
      short4v sv;
      sv[0] = f2bf(xv[j].x); sv[1] = f2bf(xv[j].y);
      sv[2] = f2bf(xv[j].z); sv[3] = f2bf(xv[j].w);
      *(short4v*)(xbr + j * 256 + lane * 4) = sv;
    }
  }
  float p[CLN];
#pragma unroll
  for (int c = 0; c < CLN; ++c) p[c] = 0.f;
#pragma unroll
  for (int j = 0; j < 4; ++j) {
    float4 cv[CLN];
#pragma unroll
    for (int c = 0; c < CLN; ++c)
      cv[c] = ((const float4*)(center + (size_t)c * DIMS))[j * 64 + lane];
#pragma unroll
    for (int c = 0; c < CLN; ++c)
      p[c] += xv[j].x * cv[c].x + xv[j].y * cv[c].y + xv[j].z * cv[c].z + xv[j].w * cv[c].w;
  }
#pragma unroll
  for (int c = 0; c < CLN; ++c) {
#pragma unroll
    for (int m = 1; m < 64; m <<= 1) p[c] += __shfl_xor(p[c], m);
  }
  if (lane == 0) {
    int best = 0; float bv = p[0];
#pragma unroll
    for (int c = 1; c < CLN; ++c) { if (p[c] > bv) { bv = p[c]; best = c; } }
    router[s] = best;
  }
}

// ---- gate body v3: gwt[c][n][k] = bf16(w0[k][n]*wc[c][k][n]) ----
// Round-9: the 2.1 TB/s invariant was issue-depth starvation — the compiler
// allocates ~40 VGPRs regardless of __launch_bounds__ budget (round-4 witness)
// and serializes register-round-trip loads (~0.2 outstanding/wave by Little's
// law). Fix: global_load_lds DMA — queue depth independent of VGPRs.
// 64k x 64n tile. Stage w0 tile + wc tile (16 KB each, fp32, linear [64][64])
// via 8 outstanding 1-KB DMA per wave; one barrier; then each thread reads
// 32 scalars, multiplies, packs, stores 32 B of the [c][n][k] output.
template <int K, int N>
__device__ __forceinline__ void gate_body(const float* __restrict__ w0,
                                          const float* __restrict__ wc,
                                          short* __restrict__ gwt, int bx,
                                          float* ldsA, float* ldsB) {
  constexpr int KB = K / 64, NB = N / 64;
  const int c = bx / (KB * NB);
  const int rem = bx % (KB * NB);
  const int k0 = (rem / NB) * 64;    // k slowest
  const int n0 = (rem % NB) * 64;    // n fastest: co-resident blocks sweep
                                     // contiguous n of the same k rows
  const int tid = threadIdx.x;
  const int lane = tid & 63;
  const int w = tid >> 6;
  // DMA stage: chunk = j*4+w covers rows 4*chunk..4*chunk+3 of the [64][64] tile.
  // lane: rrow = lane>>4 (row within chunk), rseg = lane&15 (16B n-segment).
  const int rrow = lane >> 4;
  const int rseg = lane & 15;
  const float* wcp = wc + (size_t)c * K * N;
#pragma unroll
  for (int j = 0; j < 4; ++j) {
    const int chunk = j * 4 + w;
    const size_t goff = (size_t)(k0 + chunk * 4 + rrow) * N + n0 + rseg * 4;
    gl_lds16(w0 + goff, ldsA + chunk * 256);
    gl_lds16(wcp + goff, ldsB + chunk * 256);
  }
  __syncthreads();
  // compute + transposed store: thread (n = tid>>2, seg = tid&3), k = seg*16..+16
  const int n = tid >> 2;
  const int seg = tid & 3;
  short8 o0, o1;
#pragma unroll
  for (int u = 0; u < 8; ++u) {
    const int k = seg * 16 + u;
    o0[u] = f2bf(ldsA[k * 64 + n] * ldsB[k * 64 + n]);
  }
#pragma unroll
  for (int u = 0; u < 8; ++u) {
    const int k = seg * 16 + 8 + u;
    o1[u] = f2bf(ldsA[k * 64 + n] * ldsB[k * 64 + n]);
  }
  short* dst = gwt + ((size_t)c * N + n0 + n) * K + k0 + seg * 16;
  *(short8*)dst = o0;
  *(short8*)(dst + 8) = o1;
}

// ---- fused prep: router blocks + all three gate layers ----
// Gate tiles: L0: 16*32*8=4096, L1: 32*16*8=4096, L2: 16*8*8=1024 (9216 total).
__global__ void __launch_bounds__(256, 4)
prep_kernel(const float* __restrict__ x, const float* __restrict__ center,
            int* __restrict__ router, short* __restrict__ xb,
            const float* w00, const float* wc0, short* g0,
            const float* w01, const float* wc1, short* g1,
            const float* w02, const float* wc2, short* g2) {
  __shared__ float ldsA[64 * 64];
  __shared__ float ldsB[64 * 64];
  const int bx = blockIdx.x;
  if (bx < 2048) { router_body(x, center, router, xb, bx); return; }
  const int gx = bx - 2048;
  if (gx < 4096)       gate_body<1024, 2048>(w00, wc0, g0, gx, ldsA, ldsB);
  else if (gx < 8192)  gate_body<2048, 1024>(w01, wc1, g1, gx - 4096, ldsA, ldsB);
  else                 gate_body<1024, 512>(w02, wc2, g2, gx - 8192, ldsA, ldsB);
}

// tier-1/2 standalone router
__global__ void __launch_bounds__(256, 4)
router_kernel(const float* __restrict__ x, const float* __restrict__ center,
              int* __restrict__ router, short* __restrict__ xb) {
  router_body(x, center, router, xb, blockIdx.x);
}

// tier-1 single-layer gate
template <int K, int N>
__global__ void __launch_bounds__(256, 4)
gate1_kernel(const float* __restrict__ w0, const float* __restrict__ wc,
             short* __restrict__ gwt) {
  __shared__ float ldsA[64 * 64];
  __shared__ float ldsB[64 * 64];
  gate_body<K, N>(w0, wc, gwt, blockIdx.x, ldsA, ldsB);
}

// ---- mono-block counting sort + zero z ----
__global__ void sort_kernel(const int* __restrict__ router, int* __restrict__ counts,
                            int* __restrict__ pstart, int* __restrict__ meta,
                            int* __restrict__ tile_c, int* __restrict__ tile_r,
                            int* __restrict__ order, float* __restrict__ z) {
  __shared__ int bins[CLN];
  __shared__ int cur[CLN];
  __shared__ int ps_s[CLN + 1];
  const int t = threadIdx.x;
  const int lane = t & 63;
  for (int p = t; p < PADMAX; p += 1024) z[p] = 0.f;   // gemm2 dot-accumulator
  if (t < CLN) bins[t] = 0;
  __syncthreads();
  int myc[8];
#pragma unroll
  for (int j = 0; j < 8; ++j) myc[j] = router[t + 1024 * j];
#pragma unroll
  for (int j = 0; j < 8; ++j) {
#pragma unroll
    for (int c = 0; c < CLN; ++c) {
      unsigned long long m = __ballot(myc[j] == c);
      if (lane == 0 && m) atomicAdd(&bins[c], __popcll(m));
    }
  }
  __syncthreads();
  if (t == 0) {
    int ps = 0, nt = 0;
    for (int c = 0; c < CLN; ++c) {
      const int tot = bins[c];
      counts[c] = tot; pstart[c] = ps; ps_s[c] = ps; cur[c] = 0;
      const int tiles = (tot + BM - 1) / BM;
      for (int i = 0; i < tiles; ++i) { tile_c[nt] = c; tile_r[nt] = ps + i * BM; ++nt; }
      ps += tiles * BM;
    }
    pstart[CLN] = ps; ps_s[CLN] = ps; meta[0] = nt; meta[1] = ps;
  }
  __syncthreads();
#pragma unroll
  for (int j = 0; j < 8; ++j) {
    const int s = t + 1024 * j;
    const int c = myc[j];
    int pos = 0;
#pragma unroll
    for (int cc = 0; cc < CLN; ++cc) {
      unsigned long long m = __ballot(c == cc);
      int b = 0;
      if (lane == 0 && m) b = atomicAdd(&cur[cc], __popcll(m));
      b = __shfl(b, 0);
      if (c == cc) pos = ps_s[cc] + b + __popcll(m & ((1ull << lane) - 1ull));
    }
    order[pos] = s;
  }
  __syncthreads();
  for (int p = t; p < PADMAX; p += 1024) {
#pragma unroll
    for (int c = 0; c < CLN; ++c) {
      if (p >= ps_s[c] && p < ps_s[c + 1]) {
        if (p - ps_s[c] >= bins[c]) order[p] = order[ps_s[c]];
        break;
      }
    }
  }
}

// -------- GEMM: BK=32 (round-4-measured), global_load_lds(16B), bf16 --------
// 128x128 tile, 4 waves (2x2 of 64x64), mfma_f32_16x16x32_bf16.
// 1-D grid, n0 fastest: B-slice sharers (stride NT = 0 mod 8) pin to one XCD.
// FUSE_DOT (layer 2): epilogue computes gated w3 dot per row + atomicAdd to z
// instead of writing h2 (saves 19 MB write + re-read + a kernel).
template <int K, int N, bool GATHER, bool FUSE_DOT>
__global__ void gemm_async(const short* __restrict__ Abase, const short* __restrict__ gwt,
                           short* __restrict__ Aout, const int* __restrict__ order,
                           const int* __restrict__ tile_c, const int* __restrict__ tile_r,
                           const int* __restrict__ meta,
                           const float* __restrict__ w03, const float* __restrict__ wc3,
                           float* __restrict__ z) {
  constexpr int NT = N / 128;
  const int bt = blockIdx.x / NT;
  if (bt >= meta[0]) return;
  const int n0 = (blockIdx.x % NT) * 128;
  const int cl = tile_c[bt];
  const int row0 = tile_r[bt];

  __shared__ __align__(16) short As[128 * 32];
  __shared__ __align__(16) short Bs[128 * 32];  // Bs[n][k]

  const int tid = threadIdx.x;
  const int lane = tid & 63;
  const int w = tid >> 6;
  const int wm = w >> 1;
  const int wn = w & 1;

  const int lrow = lane >> 2;
  const int kofs = (lane & 3) << 3;
  const short* ga0;
  const short* ga1;
  if (GATHER) {
    ga0 = Abase + (size_t)order[row0 + w * 16 + lrow] * K + kofs;
    ga1 = Abase + (size_t)order[row0 + 64 + w * 16 + lrow] * K + kofs;
  } else {
    ga0 = Abase + (size_t)(row0 + w * 16 + lrow) * K + kofs;
    ga1 = ga0 + (size_t)64 * K;
  }
  const short* gb0 = gwt + ((size_t)cl * N + n0 + w * 16 + lrow) * K + kofs;
  const short* gb1 = gb0 + (size_t)64 * K;
  short* lA0 = &As[w * 16 * 32];
  short* lA1 = &As[(64 + w * 16) * 32];
  short* lB0 = &Bs[w * 16 * 32];
  short* lB1 = &Bs[(64 + w * 16) * 32];

  f32x4 acc[4][4] = {};
  const int arL = wm * 64 + (lane & 15);
  const int bcL = wn * 64 + (lane & 15);
  const int kq = (lane >> 4) << 3;

  for (int kb = 0; kb < K; kb += 32) {
    __syncthreads();
    gl_lds16(ga0 + kb, lA0);
    gl_lds16(ga1 + kb, lA1);
    gl_lds16(gb0 + kb, lB0);
    gl_lds16(gb1 + kb, lB1);
    __syncthreads();

    short8 af[4], bfr[4];
#pragma unroll
    for (int mi = 0; mi < 4; ++mi) af[mi] = *(const short8*)&As[(arL + mi * 16) * 32 + kq];
#pragma unroll
    for (int ni = 0; ni < 4; ++ni) bfr[ni] = *(const short8*)&Bs[(bcL + ni * 16) * 32 + kq];
#pragma unroll
    for (int mi = 0; mi < 4; ++mi) {
#pragma unroll
      for (int ni = 0; ni < 4; ++ni) {
        acc[mi][ni] = __builtin_amdgcn_mfma_f32_16x16x32_bf16(
            __builtin_bit_cast(bf16x8, af[mi]), __builtin_bit_cast(bf16x8, bfr[ni]),
            acc[mi][ni], 0, 0, 0);
      }
    }
  }

  // C/D layout: col=lane&15, row=(lane>>4)*4+reg
  const int er = (lane >> 4) << 2;
  const int ec = lane & 15;
  if constexpr (FUSE_DOT) {
    float g[4];
#pragma unroll
    for (int ni = 0; ni < 4; ++ni) {
      const int col = n0 + wn * 64 + ni * 16 + ec;
      g[ni] = w03[col] * wc3[cl * N + col];
    }
#pragma unroll
    for (int mi = 0; mi < 4; ++mi) {
#pragma unroll
      for (int r = 0; r < 4; ++r) {
        float v = 0.f;
#pragma unroll
        for (int ni = 0; ni < 4; ++ni) v += fmaxf(acc[mi][ni][r], 0.f) * g[ni];
#pragma unroll
        for (int m = 1; m < 16; m <<= 1) v += __shfl_xor(v, m);
        if ((lane & 15) == 0)
          atomicAdd(&z[row0 + wm * 64 + mi * 16 + er + r], v);
      }
    }
  } else {
#pragma unroll
    for (int mi = 0; mi < 4; ++mi) {
#pragma unroll
      for (int ni = 0; ni < 4; ++ni) {
#pragma unroll
        for (int r = 0; r < 4; ++r) {
          float vv = fmaxf(acc[mi][ni][r], 0.f);
          const int row = row0 + wm * 64 + mi * 16 + er + r;
          const int col = n0 + wn * 64 + ni * 16 + ec;
          Aout[(size_t)row * N + col] = f2bf(vv);
        }
      }
    }
  }
}

// sigmoid + scatter to original sample slots
__global__ void final_kernel(const float* __restrict__ z, const int* __restrict__ order,
                             const int* __restrict__ meta, float* __restrict__ out) {
  const int r = blockIdx.x * 256 + threadIdx.x;
  if (r < meta[1]) out[order[r]] = 1.f / (1.f + expf(-z[r]));
}

// -------- fallback GEMM (round-1): gating fused in staging, fp32 weights --------
template <int K, int N, bool GATHER>
__global__ void gemm_layer(const float* __restrict__ Xf, const short* __restrict__ Ain,
                           const float* __restrict__ w0, const float* __restrict__ wc,
                           short* __restrict__ Aout,
                           const int* __restrict__ order,
                           const int* __restrict__ tile_c, const int* __restrict__ tile_r,
                           const int* __restrict__ meta) {
  const int bt = blockIdx.x;
  if (bt >= meta[0]) return;
  const int cl = tile_c[bt];
  const int row0 = tile_r[bt];
  const int n0 = blockIdx.y * 128;

  __shared__ __align__(16) short As[128 * 40];
  __shared__ __align__(16) short Bs[128 * 40];

  const int tid = threadIdx.x;
  const int lane = tid & 63;
  const int wm = (tid >> 6) >> 1;
  const int wn = (tid >> 6) & 1;

  f32x4 acc[4][4] = {};

  const int arow = tid >> 2;
  const int akseg = (tid & 3) << 3;
  const int bn = tid & 127;
  const int bkq = (tid >> 7) << 3;

  const float* xr0 = nullptr; const float* xr1 = nullptr;
  const short* ar0 = nullptr; const short* ar1 = nullptr;
  if (GATHER) {
    xr0 = Xf + (size_t)order[row0 + arow] * K + akseg;
    xr1 = Xf + (size_t)order[row0 + arow + 64] * K + akseg;
  } else {
    ar0 = Ain + (size_t)(row0 + arow) * K + akseg;
    ar1 = Ain + (size_t)(row0 + arow + 64) * K + akseg;
  }
  const float* w0p = w0 + n0 + bn;
  const float* wcp = wc + (size_t)cl * K * N + n0 + bn;

  for (int kb = 0; kb < K; kb += 32) {
    __syncthreads();
    if (GATHER) {
      float4 a = *(const float4*)(xr0 + kb);
      float4 b = *(const float4*)(xr0 + kb + 4);
      short8 v;
      v[0] = f2bf(a.x); v[1] = f2bf(a.y); v[2] = f2bf(a.z); v[3] = f2bf(a.w);
      v[4] = f2bf(b.x); v[5] = f2bf(b.y); v[6] = f2bf(b.z); v[7] = f2bf(b.w);
      *(short8*)&As[arow * 40 + akseg] = v;
      a = *(const float4*)(xr1 + kb);
      b = *(const float4*)(xr1 + kb + 4);
      v[0] = f2bf(a.x); v[1] = f2bf(a.y); v[2] = f2bf(a.z); v[3] = f2bf(a.w);
      v[4] = f2bf(b.x); v[5] = f2bf(b.y); v[6] = f2bf(b.z); v[7] = f2bf(b.w);
      *(short8*)&As[(arow + 64) * 40 + akseg] = v;
    } else {
      *(short8*)&As[arow * 40 + akseg] = *(const short8*)(ar0 + kb);
      *(short8*)&As[(arow + 64) * 40 + akseg] = *(const short8*)(ar1 + kb);
    }
#pragma unroll
    for (int half = 0; half < 2; ++half) {
      const int kk = bkq + half * 16;
      short8 v;
#pragma unroll
      for (int j = 0; j < 8; ++j) {
        const size_t off = (size_t)(kb + kk + j) * N;
        v[j] = f2bf(w0p[off] * wcp[off]);
      }
      *(short8*)&Bs[bn * 40 + kk] = v;
    }
    __syncthreads();

    const int arL = wm * 64 + (lane & 15);
    const int kq = (lane >> 4) << 3;
    const int bcL = wn * 64 + (lane & 15);
    short8 af[4], bfr[4];
#pragma unroll
    for (int mi = 0; mi < 4; ++mi) af[mi] = *(const short8*)&As[(arL + mi * 16) * 40 + kq];
#pragma unroll
    for (int ni = 0; ni < 4; ++ni) bfr[ni] = *(const short8*)&Bs[(bcL + ni * 16) * 40 + kq];
#pragma unroll
    for (int mi = 0; mi < 4; ++mi) {
#pragma unroll
      for (int ni = 0; ni < 4; ++ni) {
        acc[mi][ni] = __builtin_amdgcn_mfma_f32_16x16x32_bf16(
            __builtin_bit_cast(bf16x8, af[mi]), __builtin_bit_cast(bf16x8, bfr[ni]),
            acc[mi][ni], 0, 0, 0);
      }
    }
  }

  const int er = (lane >> 4) << 2;
  const int ec = lane & 15;
#pragma unroll
  for (int mi = 0; mi < 4; ++mi) {
#pragma unroll
    for (int ni = 0; ni < 4; ++ni) {
#pragma unroll
      for (int r = 0; r < 4; ++r) {
        float vv = fmaxf(acc[mi][ni][r], 0.f);
        const int row = row0 + wm * 64 + mi * 16 + er + r;
        const int col = n0 + wn * 64 + ni * 16 + ec;
        Aout[(size_t)row * N + col] = f2bf(vv);
      }
    }
  }
}

// fallback final layer (reads h2 bf16)
__global__ void layer3_kernel(const short* __restrict__ h2, const float* __restrict__ w03,
                              const float* __restrict__ wc3, const int* __restrict__ order,
                              const int* __restrict__ pstart, const int* __restrict__ meta,
                              float* __restrict__ out) {
  const int tid = threadIdx.x;
  const int lane = tid & 63;
  const int w = tid >> 6;
  const int r = blockIdx.x * 4 + w;
  if (r >= meta[1]) return;
  int c = 0;
#pragma unroll
  for (int i = 1; i < CLN; ++i) { if (r >= pstart[i]) c = i; }
  const short* hr = h2 + (size_t)r * 512;
  const int k0 = lane * 8;
  const short8 hv = *(const short8*)(hr + k0);
  const float* wcr = wc3 + c * 512;
  float part = 0.f;
#pragma unroll
  for (int j = 0; j < 8; ++j) part += bf2f(hv[j]) * w03[k0 + j] * wcr[k0 + j];
  for (int off = 32; off; off >>= 1) part += __shfl_down(part, off);
  if (lane == 0) out[order[r]] = 1.f / (1.f + expf(-part));
}

extern "C" void kernel_launch(void* const* d_in, const int* in_sizes, int n_in,
                              void* d_out, int out_size, void* d_ws, size_t ws_size,
                              hipStream_t stream) {
  const float* x = (const float*)d_in[0];
  const float* center = (const float*)d_in[1];
  const float* w0s[4]; const float* wcs[4];
  if (in_sizes[3] == 8 * in_sizes[2]) {  // dict order: w0_i, wc_i interleaved
    for (int i = 0; i < 4; ++i) { w0s[i] = (const float*)d_in[2 + 2 * i]; wcs[i] = (const float*)d_in[3 + 2 * i]; }
  } else {                               // signature order: w0_0..w0_3, wc_0..wc_3
    for (int i = 0; i < 4; ++i) { w0s[i] = (const float*)d_in[2 + i]; wcs[i] = (const float*)d_in[6 + i]; }
  }
  float* out = (float*)d_out;
  char* ws = (char*)d_ws;
  int* counts = (int*)(ws + 0);      // 8
  int* pstart = (int*)(ws + 128);    // 9
  int* meta   = (int*)(ws + 192);    // 2
  int* tile_c = (int*)(ws + 256);    // 72
  int* tile_r = (int*)(ws + 1024);   // 72
  int* router = (int*)(ws + 4096);   // 8192 ints
  int* order  = (int*)(ws + 4096 + 4 * B_SZ);         // 9216 ints
  float* z    = (float*)(ws + 4096 + 4 * B_SZ + 4 * PADMAX);  // 9216 floats, ends < 131072

  const size_t GW0 = (size_t)CLN * 1024 * 2048 * 2;   // 33.55 MB
  const size_t GW1 = (size_t)CLN * 2048 * 1024 * 2;   // 33.55 MB
  const size_t GW2 = (size_t)CLN * 1024 * 512 * 2;    // 8.39 MB
  const size_t H0B = (size_t)PADMAX * 2048 * 2;       // 37.75 MB
  const size_t H1B = (size_t)PADMAX * 1024 * 2;       // 18.87 MB (>= xb 16.8 MB)
  const size_t NEED_A = 131072 + GW0 + GW1 + GW2 + H0B + H1B;  // ~132 MB (proven fits)
  const size_t NEED_B = 131072 + GW1 + H0B + H1B;              // ~90 MB
  const int tier = (ws_size >= NEED_A) ? 0 : (ws_size >= NEED_B) ? 1 : 2;

  if (tier == 0) {
    short* gw0 = (short*)(ws + 131072);
    short* gw1 = (short*)(ws + 131072 + GW0);
    short* gw2 = (short*)(ws + 131072 + GW0 + GW1);
    short* h0  = (short*)(ws + 131072 + GW0 + GW1 + GW2);
    short* h1  = (short*)(ws + 131072 + GW0 + GW1 + GW2 + H0B);
    short* xb  = h1;   // xb lives prep->gemm0; h1 lives gemm1->gemm2 (disjoint)

    prep_kernel<<<2048 + 9216, 256, 0, stream>>>(x, center, router, xb,
                                                 w0s[0], wcs[0], gw0,
                                                 w0s[1], wcs[1], gw1,
                                                 w0s[2], wcs[2], gw2);
    sort_kernel<<<1, 1024, 0, stream>>>(router, counts, pstart, meta, tile_c, tile_r, order, z);
    gemm_async<1024, 2048, true, false><<<MAX_TILES * 16, 256, 0, stream>>>(
        xb, gw0, h0, order, tile_c, tile_r, meta, nullptr, nullptr, nullptr);
    gemm_async<2048, 1024, false, false><<<MAX_TILES * 8, 256, 0, stream>>>(
        h0, gw1, h1, order, tile_c, tile_r, meta, nullptr, nullptr, nullptr);
    gemm_async<1024, 512, false, true><<<MAX_TILES * 4, 256, 0, stream>>>(
        h1, gw2, nullptr, order, tile_c, tile_r, meta, w0s[3], wcs[3], z);
    final_kernel<<<PADMAX / 256, 256, 0, stream>>>(z, order, meta, out);
  } else if (tier == 1) {
    short* gw = (short*)(ws + 131072);
    short* h0 = (short*)(ws + 131072 + GW1);
    short* h1 = (short*)(ws + 131072 + GW1 + H0B);
    short* xb = h1;

    router_kernel<<<2048, 256, 0, stream>>>(x, center, router, xb);
    sort_kernel<<<1, 1024, 0, stream>>>(router, counts, pstart, meta, tile_c, tile_r, order, z);
    gate1_kernel<1024, 2048><<<4096, 256, 0, stream>>>(w0s[0], wcs[0], gw);
    gemm_async<1024, 2048, true, false><<<MAX_TILES * 16, 256, 0, stream>>>(
        xb, gw, h0, order, tile_c, tile_r, meta, nullptr, nullptr, nullptr);
    gate1_kernel<2048, 1024><<<4096, 256, 0, stream>>>(w0s[1], wcs[1], gw);
    gemm_async<2048, 1024, false, false><<<MAX_TILES * 8, 256, 0, stream>>>(
        h0, gw, h1, order, tile_c, tile_r, meta, nullptr, nullptr, nullptr);
    gate1_kernel<1024, 512><<<1024, 256, 0, stream>>>(w0s[2], wcs[2], gw);
    gemm_async<1024, 512, false, true><<<MAX_TILES * 4, 256, 0, stream>>>(
        h1, gw, nullptr, order, tile_c, tile_r, meta, w0s[3], wcs[3], z);
    final_kernel<<<PADMAX / 256, 256, 0, stream>>>(z, order, meta, out);
  } else {
    short* f0 = (short*)(ws + 131072);
    short* f1 = f0 + (size_t)PADMAX * 2048;
    short* f2 = f1 + (size_t)PADMAX * 1024;
    router_kernel<<<2048, 256, 0, stream>>>(x, center, router, nullptr);
    sort_kernel<<<1, 1024, 0, stream>>>(router, counts, pstart, meta, tile_c, tile_r, order, z);
    gemm_layer<1024, 2048, true><<<dim3(MAX_TILES, 16), 256, 0, stream>>>(
        x, nullptr, w0s[0], wcs[0], f0, order, tile_c, tile_r, meta);
    gemm_layer<2048, 1024, false><<<dim3(MAX_TILES, 8), 256, 0, stream>>>(
        nullptr, f0, w0s[1], wcs[1], f1, order, tile_c, tile_r, meta);
    gemm_layer<1024, 512, false><<<dim3(MAX_TILES, 4), 256, 0, stream>>>(
        nullptr, f1, w0s[2], wcs[2], f2, order, tile_c, tile_r, meta);
    layer3_kernel<<<(PADMAX + 3) / 4, 256, 0, stream>>>(f2, w0s[3], wcs[3], order, pstart, meta, out);
  }
}